// Round 12
// baseline (569.316 us; speedup 1.0000x reference)
//
#include <hip/hip_runtime.h>
#include <math.h>

#define NB 32        // batches
#define NP 512       // N == M == 512
#define RG 4         // blocks per batch
#define RPB 128      // rows per block
#define TPB 1024
#define ITERS 50
#define EPSV   0.05f
#define INVEPS 20.0f

typedef unsigned long long u64;
typedef unsigned int u32;

// ws layout: pack[2][NB][NP][RG] u32 (col-major streams -> 16B per column),
// then epi[NB][RG] float2.
// Poison safety: 0xAAAAAAAA low 3 bits = 0b010 = 2; tag set {1,3,4,5,6,7}
// never contains 2, and tag(k) != tag(k-2) (distinct nibbles, k mod 6).
// epi tag 51.0f != poison float (-3.03e-13).
#define N_PACK (2*NB*NP*RG)

// ---- relaxed agent-scope (device-coherent, MALL) primitives — the ONLY
// cross-block ops used; proven correct r2-r10. No asm, no scope tricks. ----
__device__ __forceinline__ void st32(u32* p, u32 v) {
  __hip_atomic_store(p, v, __ATOMIC_RELAXED, __HIP_MEMORY_SCOPE_AGENT);
}
__device__ __forceinline__ u64 ld64u(const u64* p) {
  return __hip_atomic_load(p, __ATOMIC_RELAXED, __HIP_MEMORY_SCOPE_AGENT);
}
__device__ __forceinline__ void st64f(float2* p, float tag, float val) {
  union { float2 f; u64 u; } c; c.f = make_float2(tag, val);
  __hip_atomic_store((u64*)p, c.u, __ATOMIC_RELAXED, __HIP_MEMORY_SCOPE_AGENT);
}
__device__ __forceinline__ float2 ld64f(const float2* p) {
  union { u64 u; float2 f; } c;
  c.u = __hip_atomic_load((const u64*)p, __ATOMIC_RELAXED, __HIP_MEMORY_SCOPE_AGENT);
  return c.f;
}

// tag for iteration k: nibble LUT over k%6 -> {1,3,4,5,6,7}
__device__ __forceinline__ u32 tag_of(int k) {
  return (0x765431u >> (4 * (k % 6))) & 0xFu;
}
// pack fp32 value with tag in low 3 mantissa bits (<=7 ulp perturbation)
__device__ __forceinline__ u32 pack_slot(float v, u32 tag) {
  return (__float_as_uint(v) & ~7u) | tag;
}

// ---------------- single fused kernel: setup + 50 linear-Sinkhorn iters + ot ----
// ONE batch per 1024-thread block, 128 rows each, RG=4 blocks/batch, grid=128
// (all blocks resident -> spin rendezvous deadlock-free).
// Exchange per iter: each block stores 512 packed 4B col-partials (its stream
// lane of each column, col-major); each thread (t<512) reads its column's 4
// streams as TWO u64 agent loads (16 contiguous bytes), polls tags, sums.
// 1 MB/iter total fetch vs r10's 4.1 MB -> coherent-path BW time ~1us/iter.
__global__ __launch_bounds__(TPB) void emd_kernel(
    const float* __restrict__ a_mask, const float* __restrict__ pc_a,
    const float* __restrict__ b_mask, const float* __restrict__ pc_b,
    u32* __restrict__ pack, float2* __restrict__ epi, float* __restrict__ out)
{
  const int bid = blockIdx.x;
  const int b   = bid >> 2;          // batch (contiguous 4-block ranges)
  const int rg  = bid & 3;           // row-group / stream index 0..3
  const int t   = threadIdx.x;
  const int chunk = t & 7;           // 8 threads per row
  const int lrow  = t >> 3;          // local row 0..127
  const int grow  = rg*RPB + lrow;   // row within batch
  const int lane  = t & 63, wid = t >> 6;   // wid 0..15
  const int ccol  = t & 511;         // C/A column
  const int half  = t >> 9;          // 0: rows [0,64), 1: rows [64,128) of block

  __shared__ __align__(16) float rho_l[NP];   // exp(logv)
  __shared__ __align__(16) float bw_l[NP];    // col masses
  __shared__ __align__(16) float u_l[RPB];    // exp(logu), this block's rows
  __shared__ __align__(16) float sm[TPB];     // setup aw (first 512) / scratch
  __shared__ float red[32];

  float4 eKreg[16];     // row slice: row=grow, cols 32*cc+4*chunk+e
  float  eKcol[64];     // col slice: col=ccol, rows rg*128+half*64+i
  float  aw_r, bw_t, hub;

  // ================= setup: masses, huber, expK caches =================
  {
    float apt = 0.f, bpt = 0.f;
    if (t < NP) {
      apt = a_mask[b*NP+t] * pc_a[((size_t)b*NP+t)*3+2];
      bpt = b_mask[b*NP+t] * pc_b[((size_t)b*NP+t)*3+2];
    }
    float ra = apt, rv = bpt;
    #pragma unroll
    for (int o = 32; o; o >>= 1) { ra += __shfl_xor(ra, o); rv += __shfl_xor(rv, o); }
    if (lane == 0) { red[wid] = ra; red[16+wid] = rv; }
    __syncthreads();
    float asum = 0.f, bsum = 0.f;
    #pragma unroll
    for (int w = 0; w < 16; ++w) { asum += red[w]; bsum += red[16+w]; }
    const float e = asum - bsum, ae = fabsf(e);
    hub = (ae <= 1.f) ? 0.5f*e*e : (ae - 0.5f);
    if (t < NP) {
      sm[t]   = (apt > 0.f) ? apt/asum : 0.f;   // aw
      bw_l[t] = (bpt > 0.f) ? bpt/bsum : 0.f;
      rho_l[t] = 1.f;                           // rho(0) = exp(0) = 1
    }
    __syncthreads();
    aw_r = sm[grow];
    bw_t = bw_l[ccol];
    const float ax = pc_a[((size_t)b*NP+grow)*3+0];
    const float ay = pc_a[((size_t)b*NP+grow)*3+1];
    const bool  va = aw_r > 0.f;
    #pragma unroll
    for (int cc = 0; cc < 16; ++cc) {
      float r[4];
      #pragma unroll
      for (int e2 = 0; e2 < 4; ++e2) {
        const int col = 32*cc + 4*chunk + e2;
        const float bx = pc_b[((size_t)b*NP+col)*3+0];
        const float by = pc_b[((size_t)b*NP+col)*3+1];
        const bool  vb = bw_l[col] > 0.f;
        const float dx = ax-bx, dy = ay-by;
        const float d  = sqrtf(dx*dx + dy*dy + 1e-12f);
        r[e2] = (va && vb) ? __expf((-INVEPS)*d) : 1.f;   // K=0 for masked pairs
      }
      eKreg[cc] = make_float4(r[0], r[1], r[2], r[3]);
    }
    const float bx0 = pc_b[((size_t)b*NP+ccol)*3+0];
    const float by0 = pc_b[((size_t)b*NP+ccol)*3+1];
    const bool  vb0 = bw_t > 0.f;
    #pragma unroll
    for (int i = 0; i < 64; ++i) {
      const int row = rg*RPB + half*64 + i;            // wave-uniform -> scalar loads
      const float axi = pc_a[((size_t)b*NP+row)*3+0];
      const float ayi = pc_a[((size_t)b*NP+row)*3+1];
      const bool  vai = sm[row] > 0.f;
      const float dx = axi-bx0, dy = ayi-by0;
      const float d  = sqrtf(dx*dx + dy*dy + 1e-12f);
      eKcol[i] = (vai && vb0) ? __expf((-INVEPS)*d) : 1.f;
    }
    __syncthreads();   // rho_l/u-scratch ready; sm(aw) reads done after this? (eKcol used sm) -- done above
  }

  // ================= main loop =================
  for (int k = 1; k <= ITERS; ++k) {
    const u32 tag = tag_of(k);
    const int par = k & 1;

    // ---- B: u(k) = aw / sum_j ek*rho(k-1)   (8-lane row dot)
    {
      const float4* r4p = (const float4*)rho_l;
      float dot = 0.f;
      #pragma unroll
      for (int cc = 0; cc < 16; ++cc) {
        const float4 g4 = r4p[8*cc + chunk];
        const float4 kk = eKreg[cc];
        dot += kk.x*g4.x + kk.y*g4.y + kk.z*g4.z + kk.w*g4.w;
      }
      #pragma unroll
      for (int o = 4; o; o >>= 1) dot += __shfl_xor(dot, o);
      if (chunk == 0) u_l[lrow] = aw_r / fmaxf(dot, 1e-38f);
    }
    __syncthreads();   // u_l ready; all rho_l reads done

    // ---- C (half-dot): sc_half = sum over my 64 rows of ek*u
    {
      const float4* u4p = (const float4*)(u_l + half*64);
      float sc = 0.f;
      #pragma unroll
      for (int i4 = 0; i4 < 16; ++i4) {
        const float4 uu = u4p[i4];
        sc += eKcol[4*i4+0]*uu.x + eKcol[4*i4+1]*uu.y
            + eKcol[4*i4+2]*uu.z + eKcol[4*i4+3]*uu.w;
      }
      sm[t] = sc;
    }
    __syncthreads();   // halves ready

    // ---- publish + A (t<512): combine halves, store packed slot, read 4 streams
    if (t < 512) {
      const float sc = sm[t] + sm[t + 512];
      u32* slot = pack + (((size_t)par*NB + b)*NP + ccol)*RG + rg;
      st32(slot, pack_slot(sc, tag));

      const u64* base64 = (const u64*)(pack + (((size_t)par*NB + b)*NP + ccol)*RG);
      u64 q0 = ld64u(base64);        // streams 0,1
      u64 q1 = ld64u(base64 + 1);    // streams 2,3
      u32 a0 = (u32)q0, a1 = (u32)(q0 >> 32);
      u32 a2 = (u32)q1, a3 = (u32)(q1 >> 32);
      long long spins = 0;
      while ((a0 & 7u) != tag || (a1 & 7u) != tag) {
        __builtin_amdgcn_s_sleep(1);
        q0 = ld64u(base64); a0 = (u32)q0; a1 = (u32)(q0 >> 32);
        if (++spins > (1LL<<27)) break;   // fail visibly, never hang
      }
      spins = 0;
      while ((a2 & 7u) != tag || (a3 & 7u) != tag) {
        __builtin_amdgcn_s_sleep(1);
        q1 = ld64u(base64 + 1); a2 = (u32)q1; a3 = (u32)(q1 >> 32);
        if (++spins > (1LL<<27)) break;
      }
      const float S = __uint_as_float(a0) + __uint_as_float(a1)
                    + __uint_as_float(a2) + __uint_as_float(a3);
      rho_l[ccol] = bw_t / fmaxf(S, 1e-38f);
    }
    __syncthreads();   // rho_l(k) ready for next B / epilogue
  }

  // ---- epilogue: ot partial = sum d^2 * u_i * ek * rho_j over my row slice
  float acc = 0.f;
  {
    const float ur = u_l[lrow];                  // u(50)
    const float4* r4p = (const float4*)rho_l;    // rho(50)
    #pragma unroll
    for (int cc = 0; cc < 16; ++cc) {
      const float4 g4 = r4p[8*cc + chunk];
      const float4 kk = eKreg[cc];
      const float ek[4] = {kk.x, kk.y, kk.z, kk.w};
      const float vv[4] = {g4.x, g4.y, g4.z, g4.w};
      #pragma unroll
      for (int e2 = 0; e2 < 4; ++e2) {
        const float lk = __logf(fmaxf(ek[e2], 1e-38f));  // d = -EPS*lk; masked: lk=0 -> d2=0
        const float d2 = (EPSV*lk)*(EPSV*lk);
        const float v  = d2 * ur * ek[e2] * vv[e2];
        acc += (ek[e2] > 0.f) ? v : 0.f;
      }
    }
  }
  // block-reduce, publish tagged epi, rg==0 gathers
  sm[t] = acc;
  __syncthreads();
  if (t < 64) {
    float v = 0.f;
    #pragma unroll
    for (int q = 0; q < 16; ++q) v += sm[t*16 + q];
    #pragma unroll
    for (int o = 32; o; o >>= 1) v += __shfl_xor(v, o);
    if (t == 0) st64f(epi + (size_t)b*RG + rg, 51.f, v);
  }
  if (rg == 0 && t < RG) {     // gather: 4 lanes, poll + shfl-reduce
    float2 pr;
    long long spins = 0;
    do {
      pr = ld64f(epi + (size_t)b*RG + t);
      if (pr.x == 51.f) break;
      __builtin_amdgcn_s_sleep(1);
    } while (++spins < (1LL<<27));
    float v = pr.y;
    #pragma unroll
    for (int o = 2; o; o >>= 1) v += __shfl_xor(v, o);
    if (t == 0) out[b] = v + hub;
  }
}

extern "C" void kernel_launch(void* const* d_in, const int* in_sizes, int n_in,
                              void* d_out, int out_size, void* d_ws, size_t ws_size,
                              hipStream_t stream) {
  const float* a_mask = (const float*)d_in[0];
  const float* pc_a   = (const float*)d_in[1];
  const float* b_mask = (const float*)d_in[2];
  const float* pc_b   = (const float*)d_in[3];
  float* out = (float*)d_out;
  u32*    pack = (u32*)d_ws;                 // 512 KiB
  float2* epi  = (float2*)(pack + N_PACK);   // + 1 KiB
  (void)in_sizes; (void)n_in; (void)out_size; (void)ws_size;

  emd_kernel<<<NB*RG, TPB, 0, stream>>>(a_mask, pc_a, b_mask, pc_b,
                                        pack, epi, out);
}

// Round 13
// 215.046 us; speedup vs baseline: 2.6474x; 2.6474x over previous
//
#include <hip/hip_runtime.h>
#include <math.h>

#define NB 32        // batches
#define NP 512       // N == M == 512
#define RG 8         // row-groups (blocks) per batch
#define RPB 64       // rows per block
#define ITERS 50
#define EPSV   0.05f
#define INVEPS 20.0f

typedef unsigned long long u64;

// ws layout (float2): parts[2][NB][RG][NP], epi[NB][RG].
// No init pass: harness poison 0xAAAAAAAA as float (-3.03e-13) never equals a
// valid tag float (1..51), so tag-gated reads are poison-safe.
#define N_PARTS (2*NB*RG*NP)

// ---- relaxed agent-scope tagged 8B exchange: tag+value arrive atomically ----
__device__ __forceinline__ void st64(float2* p, float tag, float val) {
  union { float2 f; u64 u; } c; c.f = make_float2(tag, val);
  __hip_atomic_store((u64*)p, c.u, __ATOMIC_RELAXED, __HIP_MEMORY_SCOPE_AGENT);
}
__device__ __forceinline__ float2 ld64(const float2* p) {
  union { u64 u; float2 f; } c;
  c.u = __hip_atomic_load((const u64*)p, __ATOMIC_RELAXED, __HIP_MEMORY_SCOPE_AGENT);
  return c.f;
}

// ---------------- single fused kernel: setup + 50 linear-Sinkhorn iters + ot ----
// ONE batch per 512-thread block, 64 rows each, RG=8 blocks/batch, grid=256
// (1 block/CU, all resident -> spin rendezvous deadlock-free).
// SINGLE-HOP exchange (r10 structure): C publishes tagged col-partials; each
// thread keeps its OWN partial in-register and reads only the 7 REMOTE
// streams; pending slots are re-polled as a gang (one round trip discovery).
// No min-waves launch bound: full VGPR budget keeps the 128-float eK cache
// in registers (r12 lesson: spilled eK = 2x slowdown).
__global__ __launch_bounds__(NP) void emd_kernel(
    const float* __restrict__ a_mask, const float* __restrict__ pc_a,
    const float* __restrict__ b_mask, const float* __restrict__ pc_b,
    float2* __restrict__ parts, float2* __restrict__ epi,
    float* __restrict__ out)
{
  const int rb = blockIdx.x;
  const int b  = rb >> 3;            // batch (contiguous 8-block ranges)
  const int rg = rb & 7;             // row-group 0..7
  const int t  = threadIdx.x;
  const int chunk = t & 7;           // 8 threads per row
  const int lrow  = t >> 3;          // local row 0..63
  const int grow  = rg*RPB + lrow;
  const int lane  = t & 63, wid = t >> 6;

  __shared__ __align__(16) float rho_l[NP];   // exp(logv)
  __shared__ __align__(16) float bw_l[NP];    // col masses
  __shared__ __align__(16) float u_l[RPB];    // exp(logu)
  __shared__ __align__(16) float sm[NP];      // setup aw / epilogue scratch
  __shared__ float red[16];

  float4 eKreg[16];     // row slice: row=grow, cols 32*cc+4*chunk+e
  float  eKcol[RPB];    // col slice: col=t, rows rg*64+i
  float  aw_r, bw_t, hub = 0.f;

  // ================= setup: masses, huber, expK caches =================
  {
    const float apt = a_mask[b*NP+t] * pc_a[((size_t)b*NP+t)*3+2];
    const float bpt = b_mask[b*NP+t] * pc_b[((size_t)b*NP+t)*3+2];
    float ra = apt, rv = bpt;
    #pragma unroll
    for (int o = 32; o; o >>= 1) { ra += __shfl_xor(ra, o); rv += __shfl_xor(rv, o); }
    if (lane == 0) { red[wid] = ra; red[8+wid] = rv; }
    __syncthreads();
    float asum = 0.f, bsum = 0.f;
    #pragma unroll
    for (int w = 0; w < 8; ++w) { asum += red[w]; bsum += red[8+w]; }
    const float e = asum - bsum, ae = fabsf(e);
    hub = (ae <= 1.f) ? 0.5f*e*e : (ae - 0.5f);
    sm[t]   = (apt > 0.f) ? apt/asum : 0.f;   // aw
    bw_l[t] = (bpt > 0.f) ? bpt/bsum : 0.f;
    __syncthreads();
    aw_r = sm[grow];
    bw_t = bw_l[t];
    const float ax = pc_a[((size_t)b*NP+grow)*3+0];
    const float ay = pc_a[((size_t)b*NP+grow)*3+1];
    const bool  va = aw_r > 0.f;
    #pragma unroll
    for (int cc = 0; cc < 16; ++cc) {
      float r[4];
      #pragma unroll
      for (int e2 = 0; e2 < 4; ++e2) {
        const int col = 32*cc + 4*chunk + e2;
        const float bx = pc_b[((size_t)b*NP+col)*3+0];
        const float by = pc_b[((size_t)b*NP+col)*3+1];
        const bool  vb = bw_l[col] > 0.f;
        const float dx = ax-bx, dy = ay-by;
        const float d  = sqrtf(dx*dx + dy*dy + 1e-12f);
        r[e2] = (va && vb) ? __expf((-INVEPS)*d) : 1.f;   // K=0 for masked pairs
      }
      eKreg[cc] = make_float4(r[0], r[1], r[2], r[3]);
    }
    const float bx0 = pc_b[((size_t)b*NP+t)*3+0];
    const float by0 = pc_b[((size_t)b*NP+t)*3+1];
    const bool  vb0 = bw_t > 0.f;
    #pragma unroll
    for (int i = 0; i < RPB; ++i) {
      const int row = rg*RPB + i;
      const float axi = pc_a[((size_t)b*NP+row)*3+0];  // wave-uniform -> scalar loads
      const float ayi = pc_a[((size_t)b*NP+row)*3+1];
      const bool  vai = sm[row] > 0.f;
      const float dx = axi-bx0, dy = ayi-by0;
      const float d  = sqrtf(dx*dx + dy*dy + 1e-12f);
      eKcol[i] = (vai && vb0) ? __expf((-INVEPS)*d) : 1.f;
    }
    rho_l[t] = 1.f;     // rho(0) = exp(logv=0) = 1
    __syncthreads();
  }

  // ================= main loop =================
  for (int k = 1; k <= ITERS; ++k) {
    const float tagk = (float)k;
    const int par = k & 1;

    // ---- B: u(k) = aw / sum_j ek*rho(k-1)
    {
      const float4* r4p = (const float4*)rho_l;
      float dot = 0.f;
      #pragma unroll
      for (int cc = 0; cc < 16; ++cc) {
        const float4 g4 = r4p[8*cc + chunk];
        const float4 kk = eKreg[cc];
        dot += kk.x*g4.x + kk.y*g4.y + kk.z*g4.z + kk.w*g4.w;
      }
      #pragma unroll
      for (int o = 4; o; o >>= 1) dot += __shfl_xor(dot, o);   // 8-lane row reduce
      if (chunk == 0) u_l[lrow] = aw_r / fmaxf(dot, 1e-38f);
    }
    __syncthreads();   // u_l ready (also: all rho_l reads done)

    // ---- C: publish tagged col partial s(k) for col t; keep own value local
    float sc_own;
    {
      const float4* u4p = (const float4*)u_l;
      float sc = 0.f;
      #pragma unroll
      for (int i4 = 0; i4 < 16; ++i4) {
        const float4 uu = u4p[i4];
        sc += eKcol[4*i4+0]*uu.x + eKcol[4*i4+1]*uu.y
            + eKcol[4*i4+2]*uu.z + eKcol[4*i4+3]*uu.w;
      }
      sc_own = sc;
      st64(parts + (((size_t)par*NB + b)*RG + rg)*NP + t, tagk, sc);
    }

    // ---- A (single hop): read the 7 REMOTE streams for col t; gang re-poll
    {
      const float2* base = parts + ((size_t)par*NB + b)*RG*NP + t;
      float2 q[RG];
      #pragma unroll
      for (int r = 0; r < RG; ++r)
        if (r != rg) q[r] = ld64(base + (size_t)r*NP);   // 7 loads in flight
      unsigned pend = 0xFFu & ~(1u << rg);
      long long sweeps = 0;
      while (true) {
        unsigned np = 0;
        #pragma unroll
        for (int r = 0; r < RG; ++r)
          if ((pend >> r) & 1u)
            if (q[r].x != tagk) np |= (1u << r);
        pend = np;
        if (!pend) break;
        __builtin_amdgcn_s_sleep(1);
        #pragma unroll
        for (int r = 0; r < RG; ++r)        // re-issue ALL pending together
          if ((pend >> r) & 1u) q[r] = ld64(base + (size_t)r*NP);
        if (++sweeps > (1LL<<24)) break;    // fail visibly, never hang
      }
      float S = sc_own;
      #pragma unroll
      for (int r = 0; r < RG; ++r)
        if (r != rg) S += q[r].y;
      rho_l[t] = bw_t / fmaxf(S, 1e-38f);
    }
    __syncthreads();   // rho_l(k) ready for next B / epilogue
  }

  // ---- epilogue: ot partial = sum d^2 * u_i * ek * rho_j over my row slice
  float acc = 0.f;
  {
    const float ur = u_l[lrow];                  // u(50)
    const float4* r4p = (const float4*)rho_l;    // rho(50)
    #pragma unroll
    for (int cc = 0; cc < 16; ++cc) {
      const float4 g4 = r4p[8*cc + chunk];
      const float4 kk = eKreg[cc];
      const float ek[4] = {kk.x, kk.y, kk.z, kk.w};
      const float vv[4] = {g4.x, g4.y, g4.z, g4.w};
      #pragma unroll
      for (int e2 = 0; e2 < 4; ++e2) {
        const float lk = __logf(fmaxf(ek[e2], 1e-38f));  // d = -EPS*lk; masked: lk=0 -> d2=0
        const float d2 = (EPSV*lk)*(EPSV*lk);
        const float v  = d2 * ur * ek[e2] * vv[e2];
        acc += (ek[e2] > 0.f) ? v : 0.f;
      }
    }
  }
  // block-reduce, publish tagged epi, rg==0 gathers
  sm[t] = acc;
  __syncthreads();
  if (t < 64) {
    float v = 0.f;
    #pragma unroll
    for (int q = 0; q < 8; ++q) v += sm[t*8+q];
    #pragma unroll
    for (int o = 32; o; o >>= 1) v += __shfl_xor(v, o);
    if (t == 0) st64(epi + (size_t)b*RG + rg, 51.f, v);
  }
  if (rg == 0 && t < RG) {     // gather: 8 lanes, poll + shfl-reduce
    float2 pr;
    long long spins = 0;
    do {
      pr = ld64(epi + (size_t)b*RG + t);
      if (pr.x == 51.f) break;
      __builtin_amdgcn_s_sleep(1);
    } while (++spins < (1LL<<27));
    float v = pr.y;
    #pragma unroll
    for (int o = 4; o; o >>= 1) v += __shfl_xor(v, o);
    if (t == 0) out[b] = v + hub;
  }
}

extern "C" void kernel_launch(void* const* d_in, const int* in_sizes, int n_in,
                              void* d_out, int out_size, void* d_ws, size_t ws_size,
                              hipStream_t stream) {
  const float* a_mask = (const float*)d_in[0];
  const float* pc_a   = (const float*)d_in[1];
  const float* b_mask = (const float*)d_in[2];
  const float* pc_b   = (const float*)d_in[3];
  float* out = (float*)d_out;
  float2* parts = (float2*)d_ws;            // 2 MiB
  float2* epi   = parts + N_PARTS;          // + 2 KiB
  (void)in_sizes; (void)n_in; (void)out_size; (void)ws_size;

  emd_kernel<<<NB*RG, NP, 0, stream>>>(a_mask, pc_a, b_mask, pc_b,
                                       parts, epi, out);
}

// Round 14
// 202.990 us; speedup vs baseline: 2.8047x; 1.0594x over previous
//
#include <hip/hip_runtime.h>
#include <math.h>

#define NB 32        // batches
#define NP 512       // N == M == 512
#define RG 8         // row-groups (blocks) per batch
#define RPB 64       // rows per block
#define ITERS 50
#define EPSV   0.05f
#define INVEPS 20.0f

typedef unsigned long long u64;
typedef unsigned int u32;

// ws layout: pack[2][NB][RG][NP] u32 (row-major: each 512-col stream is a
// contiguous single-writer array -> no false sharing), then epi[NB][RG] float2.
// Poison safety: 0xAAAAAAAA low 3 bits = 2; tag set {1,3,4,5,6,7} never
// contains 2 and tag(k) != tag(k-2) (k mod 6 LUT). epi tag 51.0f != poison.
#define N_PACK (2*NB*RG*NP)

// ---- relaxed agent-scope (device-coherent) primitives ----
__device__ __forceinline__ void st32(u32* p, u32 v) {
  __hip_atomic_store(p, v, __ATOMIC_RELAXED, __HIP_MEMORY_SCOPE_AGENT);
}
__device__ __forceinline__ u32 ld32(const u32* p) {
  return __hip_atomic_load(p, __ATOMIC_RELAXED, __HIP_MEMORY_SCOPE_AGENT);
}
__device__ __forceinline__ void st64f(float2* p, float tag, float val) {
  union { float2 f; u64 u; } c; c.f = make_float2(tag, val);
  __hip_atomic_store((u64*)p, c.u, __ATOMIC_RELAXED, __HIP_MEMORY_SCOPE_AGENT);
}
__device__ __forceinline__ float2 ld64f(const float2* p) {
  union { u64 u; float2 f; } c;
  c.u = __hip_atomic_load((const u64*)p, __ATOMIC_RELAXED, __HIP_MEMORY_SCOPE_AGENT);
  return c.f;
}

// tag for iteration k: nibble LUT over k%6 -> {1,3,4,5,6,7} (proven r12)
__device__ __forceinline__ u32 tag_of(int k) {
  return (0x765431u >> (4 * (k % 6))) & 0xFu;
}
// pack fp32 value with tag in low 3 mantissa bits (<=7 ulp perturbation)
__device__ __forceinline__ u32 pack_slot(float v, u32 tag) {
  return (__float_as_uint(v) & ~7u) | tag;
}

// ---------------- single fused kernel: setup + 50 linear-Sinkhorn iters + ot ----
// ONE batch per 512-thread block, 64 rows each, RG=8 blocks/batch, grid=256
// (1 block/CU, all resident -> spin rendezvous deadlock-free).
// r13 structure: single-hop exchange, own stream kept in-register, 7 remote
// 4-BYTE packed slots read per thread, gang re-poll (one-round-trip discovery).
__global__ __launch_bounds__(NP) void emd_kernel(
    const float* __restrict__ a_mask, const float* __restrict__ pc_a,
    const float* __restrict__ b_mask, const float* __restrict__ pc_b,
    u32* __restrict__ pack, float2* __restrict__ epi,
    float* __restrict__ out)
{
  const int rb = blockIdx.x;
  const int b  = rb >> 3;            // batch (contiguous 8-block ranges)
  const int rg = rb & 7;             // row-group 0..7
  const int t  = threadIdx.x;
  const int chunk = t & 7;           // 8 threads per row
  const int lrow  = t >> 3;          // local row 0..63
  const int grow  = rg*RPB + lrow;
  const int lane  = t & 63, wid = t >> 6;

  __shared__ __align__(16) float rho_l[NP];   // exp(logv)
  __shared__ __align__(16) float bw_l[NP];    // col masses
  __shared__ __align__(16) float u_l[RPB];    // exp(logu)
  __shared__ __align__(16) float sm[NP];      // setup aw / epilogue scratch
  __shared__ float red[16];

  float4 eKreg[16];     // row slice: row=grow, cols 32*cc+4*chunk+e
  float  eKcol[RPB];    // col slice: col=t, rows rg*64+i
  float  aw_r, bw_t, hub = 0.f;

  // ================= setup: masses, huber, expK caches =================
  {
    const float apt = a_mask[b*NP+t] * pc_a[((size_t)b*NP+t)*3+2];
    const float bpt = b_mask[b*NP+t] * pc_b[((size_t)b*NP+t)*3+2];
    float ra = apt, rv = bpt;
    #pragma unroll
    for (int o = 32; o; o >>= 1) { ra += __shfl_xor(ra, o); rv += __shfl_xor(rv, o); }
    if (lane == 0) { red[wid] = ra; red[8+wid] = rv; }
    __syncthreads();
    float asum = 0.f, bsum = 0.f;
    #pragma unroll
    for (int w = 0; w < 8; ++w) { asum += red[w]; bsum += red[8+w]; }
    const float e = asum - bsum, ae = fabsf(e);
    hub = (ae <= 1.f) ? 0.5f*e*e : (ae - 0.5f);
    sm[t]   = (apt > 0.f) ? apt/asum : 0.f;   // aw
    bw_l[t] = (bpt > 0.f) ? bpt/bsum : 0.f;
    __syncthreads();
    aw_r = sm[grow];
    bw_t = bw_l[t];
    const float ax = pc_a[((size_t)b*NP+grow)*3+0];
    const float ay = pc_a[((size_t)b*NP+grow)*3+1];
    const bool  va = aw_r > 0.f;
    #pragma unroll
    for (int cc = 0; cc < 16; ++cc) {
      float r[4];
      #pragma unroll
      for (int e2 = 0; e2 < 4; ++e2) {
        const int col = 32*cc + 4*chunk + e2;
        const float bx = pc_b[((size_t)b*NP+col)*3+0];
        const float by = pc_b[((size_t)b*NP+col)*3+1];
        const bool  vb = bw_l[col] > 0.f;
        const float dx = ax-bx, dy = ay-by;
        const float d  = sqrtf(dx*dx + dy*dy + 1e-12f);
        r[e2] = (va && vb) ? __expf((-INVEPS)*d) : 1.f;   // K=0 for masked pairs
      }
      eKreg[cc] = make_float4(r[0], r[1], r[2], r[3]);
    }
    const float bx0 = pc_b[((size_t)b*NP+t)*3+0];
    const float by0 = pc_b[((size_t)b*NP+t)*3+1];
    const bool  vb0 = bw_t > 0.f;
    #pragma unroll
    for (int i = 0; i < RPB; ++i) {
      const int row = rg*RPB + i;
      const float axi = pc_a[((size_t)b*NP+row)*3+0];  // wave-uniform -> scalar loads
      const float ayi = pc_a[((size_t)b*NP+row)*3+1];
      const bool  vai = sm[row] > 0.f;
      const float dx = axi-bx0, dy = ayi-by0;
      const float d  = sqrtf(dx*dx + dy*dy + 1e-12f);
      eKcol[i] = (vai && vb0) ? __expf((-INVEPS)*d) : 1.f;
    }
    rho_l[t] = 1.f;     // rho(0) = exp(logv=0) = 1
    __syncthreads();
  }

  // ================= main loop =================
  for (int k = 1; k <= ITERS; ++k) {
    const u32 tag = tag_of(k);
    const int par = k & 1;

    // ---- B: u(k) = aw / sum_j ek*rho(k-1)
    {
      const float4* r4p = (const float4*)rho_l;
      float dot = 0.f;
      #pragma unroll
      for (int cc = 0; cc < 16; ++cc) {
        const float4 g4 = r4p[8*cc + chunk];
        const float4 kk = eKreg[cc];
        dot += kk.x*g4.x + kk.y*g4.y + kk.z*g4.z + kk.w*g4.w;
      }
      #pragma unroll
      for (int o = 4; o; o >>= 1) dot += __shfl_xor(dot, o);   // 8-lane row reduce
      if (chunk == 0) u_l[lrow] = aw_r / fmaxf(dot, 1e-38f);
    }
    __syncthreads();   // u_l ready (also: all rho_l reads done)

    // ---- C: publish packed col partial s(k) for col t; keep own value local
    float sc_own;
    {
      const float4* u4p = (const float4*)u_l;
      float sc = 0.f;
      #pragma unroll
      for (int i4 = 0; i4 < 16; ++i4) {
        const float4 uu = u4p[i4];
        sc += eKcol[4*i4+0]*uu.x + eKcol[4*i4+1]*uu.y
            + eKcol[4*i4+2]*uu.z + eKcol[4*i4+3]*uu.w;
      }
      sc_own = sc;
      st32(pack + (((size_t)par*NB + b)*RG + rg)*NP + t, pack_slot(sc, tag));
    }

    // ---- A (single hop): read the 7 REMOTE packed streams; gang re-poll
    {
      const u32* base = pack + ((size_t)par*NB + b)*RG*NP + t;
      u32 q[RG];
      #pragma unroll
      for (int r = 0; r < RG; ++r)
        if (r != rg) q[r] = ld32(base + (size_t)r*NP);   // 7 loads in flight
      unsigned pend = 0xFFu & ~(1u << rg);
      long long sweeps = 0;
      while (true) {
        unsigned np = 0;
        #pragma unroll
        for (int r = 0; r < RG; ++r)
          if ((pend >> r) & 1u)
            if ((q[r] & 7u) != tag) np |= (1u << r);
        pend = np;
        if (!pend) break;
        __builtin_amdgcn_s_sleep(1);
        #pragma unroll
        for (int r = 0; r < RG; ++r)        // re-issue ALL pending together
          if ((pend >> r) & 1u) q[r] = ld32(base + (size_t)r*NP);
        if (++sweeps > (1LL<<24)) break;    // fail visibly, never hang
      }
      float S = sc_own;
      #pragma unroll
      for (int r = 0; r < RG; ++r)
        if (r != rg) S += __uint_as_float(q[r]);   // <=7 ulp tag noise
      rho_l[t] = bw_t / fmaxf(S, 1e-38f);
    }
    __syncthreads();   // rho_l(k) ready for next B / epilogue
  }

  // ---- epilogue: ot partial = sum d^2 * u_i * ek * rho_j over my row slice
  float acc = 0.f;
  {
    const float ur = u_l[lrow];                  // u(50)
    const float4* r4p = (const float4*)rho_l;    // rho(50)
    #pragma unroll
    for (int cc = 0; cc < 16; ++cc) {
      const float4 g4 = r4p[8*cc + chunk];
      const float4 kk = eKreg[cc];
      const float ek[4] = {kk.x, kk.y, kk.z, kk.w};
      const float vv[4] = {g4.x, g4.y, g4.z, g4.w};
      #pragma unroll
      for (int e2 = 0; e2 < 4; ++e2) {
        const float lk = __logf(fmaxf(ek[e2], 1e-38f));  // d = -EPS*lk; masked: lk=0 -> d2=0
        const float d2 = (EPSV*lk)*(EPSV*lk);
        const float v  = d2 * ur * ek[e2] * vv[e2];
        acc += (ek[e2] > 0.f) ? v : 0.f;
      }
    }
  }
  // block-reduce, publish tagged epi, rg==0 gathers
  sm[t] = acc;
  __syncthreads();
  if (t < 64) {
    float v = 0.f;
    #pragma unroll
    for (int q = 0; q < 8; ++q) v += sm[t*8+q];
    #pragma unroll
    for (int o = 32; o; o >>= 1) v += __shfl_xor(v, o);
    if (t == 0) st64f(epi + (size_t)b*RG + rg, 51.f, v);
  }
  if (rg == 0 && t < RG) {     // gather: 8 lanes, poll + shfl-reduce
    float2 pr;
    long long spins = 0;
    do {
      pr = ld64f(epi + (size_t)b*RG + t);
      if (pr.x == 51.f) break;
      __builtin_amdgcn_s_sleep(1);
    } while (++spins < (1LL<<27));
    float v = pr.y;
    #pragma unroll
    for (int o = 4; o; o >>= 1) v += __shfl_xor(v, o);
    if (t == 0) out[b] = v + hub;
  }
}

extern "C" void kernel_launch(void* const* d_in, const int* in_sizes, int n_in,
                              void* d_out, int out_size, void* d_ws, size_t ws_size,
                              hipStream_t stream) {
  const float* a_mask = (const float*)d_in[0];
  const float* pc_a   = (const float*)d_in[1];
  const float* b_mask = (const float*)d_in[2];
  const float* pc_b   = (const float*)d_in[3];
  float* out = (float*)d_out;
  u32*    pack = (u32*)d_ws;                 // 1 MiB
  float2* epi  = (float2*)(pack + N_PACK);   // + 2 KiB
  (void)in_sizes; (void)n_in; (void)out_size; (void)ws_size;

  emd_kernel<<<NB*RG, NP, 0, stream>>>(a_mask, pc_a, b_mask, pc_b,
                                       pack, epi, out);
}

// Round 15
// 202.598 us; speedup vs baseline: 2.8101x; 1.0019x over previous
//
#include <hip/hip_runtime.h>
#include <math.h>

#define NB 32        // batches
#define NP 512       // N == M == 512
#define RG 8         // row-groups (blocks) per batch
#define RPB 64       // rows per block
#define ITERS 50
#define EPSV   0.05f
#define INVEPS 20.0f

typedef unsigned long long u64;
typedef unsigned int u32;

// ws layout: pack[2][NB][RG][NP] u32 (row-major: each 512-col stream is a
// contiguous single-writer array -> no false sharing), then epi[NB][RG] float2.
// Poison safety: 0xAAAAAAAA low 3 bits = 2; tag set {1,3,4,5,6,7} never
// contains 2 and tag(k) != tag(k-2) (k mod 6 LUT). epi tag 51.0f != poison.
#define N_PACK (2*NB*RG*NP)

// ---- relaxed agent-scope (device-coherent) primitives ----
__device__ __forceinline__ void st32(u32* p, u32 v) {
  __hip_atomic_store(p, v, __ATOMIC_RELAXED, __HIP_MEMORY_SCOPE_AGENT);
}
__device__ __forceinline__ u32 ld32(const u32* p) {
  return __hip_atomic_load(p, __ATOMIC_RELAXED, __HIP_MEMORY_SCOPE_AGENT);
}
__device__ __forceinline__ void st64f(float2* p, float tag, float val) {
  union { float2 f; u64 u; } c; c.f = make_float2(tag, val);
  __hip_atomic_store((u64*)p, c.u, __ATOMIC_RELAXED, __HIP_MEMORY_SCOPE_AGENT);
}
__device__ __forceinline__ float2 ld64f(const float2* p) {
  union { u64 u; float2 f; } c;
  c.u = __hip_atomic_load((const u64*)p, __ATOMIC_RELAXED, __HIP_MEMORY_SCOPE_AGENT);
  return c.f;
}

// tag for iteration k: nibble LUT over k%6 -> {1,3,4,5,6,7} (proven r12/r14)
__device__ __forceinline__ u32 tag_of(int k) {
  return (0x765431u >> (4 * (k % 6))) & 0xFu;
}
// pack fp32 value with tag in low 3 mantissa bits (<=7 ulp perturbation)
__device__ __forceinline__ u32 pack_slot(float v, u32 tag) {
  return (__float_as_uint(v) & ~7u) | tag;
}

// ---------------- single fused kernel: setup + 50 linear-Sinkhorn iters + ot ----
// ONE batch per 512-thread block, 64 rows each, RG=8 blocks/batch, grid=256
// (1 block/CU, all resident -> spin rendezvous deadlock-free).
// r14 structure + two latency cuts:
//  (1) SPECULATIVE early issue: the 7 remote stream loads for iteration k are
//      issued at the TOP of B(k) (tag-checked later; tag(k)!=tag(k-2) makes
//      stale detection exact) -> peers that ran ahead are discovered for free,
//      overlapped with B+C compute.
//  (2) sleep-free gang re-poll: the ~600cyc load RT is itself the backoff.
__global__ __launch_bounds__(NP) void emd_kernel(
    const float* __restrict__ a_mask, const float* __restrict__ pc_a,
    const float* __restrict__ b_mask, const float* __restrict__ pc_b,
    u32* __restrict__ pack, float2* __restrict__ epi,
    float* __restrict__ out)
{
  const int rb = blockIdx.x;
  const int b  = rb >> 3;            // batch (contiguous 8-block ranges)
  const int rg = rb & 7;             // row-group 0..7
  const int t  = threadIdx.x;
  const int chunk = t & 7;           // 8 threads per row
  const int lrow  = t >> 3;          // local row 0..63
  const int grow  = rg*RPB + lrow;
  const int lane  = t & 63, wid = t >> 6;

  __shared__ __align__(16) float rho_l[NP];   // exp(logv)
  __shared__ __align__(16) float bw_l[NP];    // col masses
  __shared__ __align__(16) float u_l[RPB];    // exp(logu)
  __shared__ __align__(16) float sm[NP];      // setup aw / epilogue scratch
  __shared__ float red[16];

  float4 eKreg[16];     // row slice: row=grow, cols 32*cc+4*chunk+e
  float  eKcol[RPB];    // col slice: col=t, rows rg*64+i
  float  aw_r, bw_t, hub = 0.f;

  // ================= setup: masses, huber, expK caches =================
  {
    const float apt = a_mask[b*NP+t] * pc_a[((size_t)b*NP+t)*3+2];
    const float bpt = b_mask[b*NP+t] * pc_b[((size_t)b*NP+t)*3+2];
    float ra = apt, rv = bpt;
    #pragma unroll
    for (int o = 32; o; o >>= 1) { ra += __shfl_xor(ra, o); rv += __shfl_xor(rv, o); }
    if (lane == 0) { red[wid] = ra; red[8+wid] = rv; }
    __syncthreads();
    float asum = 0.f, bsum = 0.f;
    #pragma unroll
    for (int w = 0; w < 8; ++w) { asum += red[w]; bsum += red[8+w]; }
    const float e = asum - bsum, ae = fabsf(e);
    hub = (ae <= 1.f) ? 0.5f*e*e : (ae - 0.5f);
    sm[t]   = (apt > 0.f) ? apt/asum : 0.f;   // aw
    bw_l[t] = (bpt > 0.f) ? bpt/bsum : 0.f;
    __syncthreads();
    aw_r = sm[grow];
    bw_t = bw_l[t];
    const float ax = pc_a[((size_t)b*NP+grow)*3+0];
    const float ay = pc_a[((size_t)b*NP+grow)*3+1];
    const bool  va = aw_r > 0.f;
    #pragma unroll
    for (int cc = 0; cc < 16; ++cc) {
      float r[4];
      #pragma unroll
      for (int e2 = 0; e2 < 4; ++e2) {
        const int col = 32*cc + 4*chunk + e2;
        const float bx = pc_b[((size_t)b*NP+col)*3+0];
        const float by = pc_b[((size_t)b*NP+col)*3+1];
        const bool  vb = bw_l[col] > 0.f;
        const float dx = ax-bx, dy = ay-by;
        const float d  = sqrtf(dx*dx + dy*dy + 1e-12f);
        r[e2] = (va && vb) ? __expf((-INVEPS)*d) : 1.f;   // K=0 for masked pairs
      }
      eKreg[cc] = make_float4(r[0], r[1], r[2], r[3]);
    }
    const float bx0 = pc_b[((size_t)b*NP+t)*3+0];
    const float by0 = pc_b[((size_t)b*NP+t)*3+1];
    const bool  vb0 = bw_t > 0.f;
    #pragma unroll
    for (int i = 0; i < RPB; ++i) {
      const int row = rg*RPB + i;
      const float axi = pc_a[((size_t)b*NP+row)*3+0];  // wave-uniform -> scalar loads
      const float ayi = pc_a[((size_t)b*NP+row)*3+1];
      const bool  vai = sm[row] > 0.f;
      const float dx = axi-bx0, dy = ayi-by0;
      const float d  = sqrtf(dx*dx + dy*dy + 1e-12f);
      eKcol[i] = (vai && vb0) ? __expf((-INVEPS)*d) : 1.f;
    }
    rho_l[t] = 1.f;     // rho(0) = exp(logv=0) = 1
    __syncthreads();
  }

  // ================= main loop =================
  for (int k = 1; k <= ITERS; ++k) {
    const u32 tag = tag_of(k);
    const int par = k & 1;
    const u32* base = pack + ((size_t)par*NB + b)*RG*NP + t;

    // ---- speculative early issue of the 7 remote streams for THIS iteration
    u32 q[RG];
    #pragma unroll
    for (int r = 0; r < RG; ++r)
      if (r != rg) q[r] = ld32(base + (size_t)r*NP);

    // ---- B: u(k) = aw / sum_j ek*rho(k-1)
    {
      const float4* r4p = (const float4*)rho_l;
      float dot = 0.f;
      #pragma unroll
      for (int cc = 0; cc < 16; ++cc) {
        const float4 g4 = r4p[8*cc + chunk];
        const float4 kk = eKreg[cc];
        dot += kk.x*g4.x + kk.y*g4.y + kk.z*g4.z + kk.w*g4.w;
      }
      #pragma unroll
      for (int o = 4; o; o >>= 1) dot += __shfl_xor(dot, o);   // 8-lane row reduce
      if (chunk == 0) u_l[lrow] = aw_r / fmaxf(dot, 1e-38f);
    }
    __syncthreads();   // u_l ready (also: all rho_l reads done)

    // ---- C: publish packed col partial s(k) for col t; keep own value local
    float sc_own;
    {
      const float4* u4p = (const float4*)u_l;
      float sc = 0.f;
      #pragma unroll
      for (int i4 = 0; i4 < 16; ++i4) {
        const float4 uu = u4p[i4];
        sc += eKcol[4*i4+0]*uu.x + eKcol[4*i4+1]*uu.y
            + eKcol[4*i4+2]*uu.z + eKcol[4*i4+3]*uu.w;
      }
      sc_own = sc;
      st32(pack + (((size_t)par*NB + b)*RG + rg)*NP + t, pack_slot(sc, tag));
    }

    // ---- A: check speculative results; sleep-free gang re-poll of laggards
    {
      unsigned pend = 0xFFu & ~(1u << rg);
      long long sweeps = 0;
      while (true) {
        unsigned np = 0;
        #pragma unroll
        for (int r = 0; r < RG; ++r)
          if ((pend >> r) & 1u)
            if ((q[r] & 7u) != tag) np |= (1u << r);
        pend = np;
        if (!pend) break;
        #pragma unroll
        for (int r = 0; r < RG; ++r)        // re-issue ALL pending together;
          if ((pend >> r) & 1u)             // load RT is the natural backoff
            q[r] = ld32(base + (size_t)r*NP);
        if (++sweeps > (1LL<<24)) break;    // fail visibly, never hang
      }
      float S = sc_own;
      #pragma unroll
      for (int r = 0; r < RG; ++r)
        if (r != rg) S += __uint_as_float(q[r]);   // <=7 ulp tag noise
      rho_l[t] = bw_t / fmaxf(S, 1e-38f);
    }
    __syncthreads();   // rho_l(k) ready for next B / epilogue
  }

  // ---- epilogue: ot partial = sum d^2 * u_i * ek * rho_j over my row slice
  float acc = 0.f;
  {
    const float ur = u_l[lrow];                  // u(50)
    const float4* r4p = (const float4*)rho_l;    // rho(50)
    #pragma unroll
    for (int cc = 0; cc < 16; ++cc) {
      const float4 g4 = r4p[8*cc + chunk];
      const float4 kk = eKreg[cc];
      const float ek[4] = {kk.x, kk.y, kk.z, kk.w};
      const float vv[4] = {g4.x, g4.y, g4.z, g4.w};
      #pragma unroll
      for (int e2 = 0; e2 < 4; ++e2) {
        const float lk = __logf(fmaxf(ek[e2], 1e-38f));  // d = -EPS*lk; masked: lk=0 -> d2=0
        const float d2 = (EPSV*lk)*(EPSV*lk);
        const float v  = d2 * ur * ek[e2] * vv[e2];
        acc += (ek[e2] > 0.f) ? v : 0.f;
      }
    }
  }
  // block-reduce, publish tagged epi, rg==0 gathers
  sm[t] = acc;
  __syncthreads();
  if (t < 64) {
    float v = 0.f;
    #pragma unroll
    for (int q = 0; q < 8; ++q) v += sm[t*8+q];
    #pragma unroll
    for (int o = 32; o; o >>= 1) v += __shfl_xor(v, o);
    if (t == 0) st64f(epi + (size_t)b*RG + rg, 51.f, v);
  }
  if (rg == 0 && t < RG) {     // gather: 8 lanes, poll + shfl-reduce
    float2 pr;
    long long spins = 0;
    do {
      pr = ld64f(epi + (size_t)b*RG + t);
      if (pr.x == 51.f) break;
      __builtin_amdgcn_s_sleep(1);
    } while (++spins < (1LL<<27));
    float v = pr.y;
    #pragma unroll
    for (int o = 4; o; o >>= 1) v += __shfl_xor(v, o);
    if (t == 0) out[b] = v + hub;
  }
}

extern "C" void kernel_launch(void* const* d_in, const int* in_sizes, int n_in,
                              void* d_out, int out_size, void* d_ws, size_t ws_size,
                              hipStream_t stream) {
  const float* a_mask = (const float*)d_in[0];
  const float* pc_a   = (const float*)d_in[1];
  const float* b_mask = (const float*)d_in[2];
  const float* pc_b   = (const float*)d_in[3];
  float* out = (float*)d_out;
  u32*    pack = (u32*)d_ws;                 // 1 MiB
  float2* epi  = (float2*)(pack + N_PACK);   // + 2 KiB
  (void)in_sizes; (void)n_in; (void)out_size; (void)ws_size;

  emd_kernel<<<NB*RG, NP, 0, stream>>>(a_mask, pc_a, b_mask, pc_b,
                                       pack, epi, out);
}